// Round 2
// baseline (517.914 us; speedup 1.0000x reference)
//
#include <hip/hip_runtime.h>
#include <math.h>

// ---------------------------------------------------------------------------
// 2-layer GAT on MI355X.
// Layer: z = h@W.T ; zi = h@U.T ; e = lrelu(zs[src]+zd[dst]+d*V*a[2D])
//        segment-softmax over dst ; out = relu(zi + sum(alpha*z[src]))
// Workspace-size-aware: z stored f32 (tier A) or bf16 (tier B) so the carve
// always fits inside ws_size (Round-1 failure was ws overflow corrupting
// neighboring buffers -> post-timing divergence).
// ---------------------------------------------------------------------------

#define D 128

static __device__ __forceinline__ float lrelu(float x) {
  return x >= 0.f ? x : 0.01f * x;
}

// ---- z-storage abstraction (float or bf16-in-ushort) ----------------------
static __device__ __forceinline__ void storeZ(float* p, float v) { *p = v; }
static __device__ __forceinline__ void storeZ(unsigned short* p, float v) {
  unsigned int u = __float_as_uint(v);
  u += 0x7fffu + ((u >> 16) & 1u);  // round-to-nearest-even
  *p = (unsigned short)(u >> 16);
}
static __device__ __forceinline__ float2 loadZ2(const float* p) {
  return *(const float2*)p;
}
static __device__ __forceinline__ float2 loadZ2(const unsigned short* p) {
  ushort2 t = *(const ushort2*)p;
  return make_float2(__uint_as_float((unsigned int)t.x << 16),
                     __uint_as_float((unsigned int)t.y << 16));
}

// ---------------- GEMM: C[r][j] = sum_k A[r][k] * B[j][k] ------------------
// A: [rows,128] f32, B: [128,128] f32 row-major. Block: 256 thr,
// tile 32 rows x 64 cols (grid.y=2 picks col half). C: float or bf16.
template <typename ZT>
__global__ __launch_bounds__(256) void gemm_rowdot(
    const float* __restrict__ A, const float* __restrict__ B,
    ZT* __restrict__ C, int rows) {
  __shared__ float As[32][132];
  __shared__ float Ws[64][132];
  const int t = threadIdx.x;
  const int r0 = blockIdx.x * 32;
  const int jb = blockIdx.y * 64;

#pragma unroll
  for (int i = 0; i < 4; ++i) {
    int v = t + i * 256;
    int row = v >> 5, kq = v & 31;
    float4 val = make_float4(0.f, 0.f, 0.f, 0.f);
    if (r0 + row < rows)
      val = *(const float4*)&A[(size_t)(r0 + row) * D + kq * 4];
    *(float4*)&As[row][kq * 4] = val;
  }
#pragma unroll
  for (int i = 0; i < 8; ++i) {
    int v = t + i * 256;
    int row = v >> 5, kq = v & 31;
    float4 val = *(const float4*)&B[(size_t)(jb + row) * D + kq * 4];
    *(float4*)&Ws[row][kq * 4] = val;
  }
  __syncthreads();

  const int tx = t & 31, ty = t >> 5;
  float acc[4][2] = {};
#pragma unroll 8
  for (int kq = 0; kq < 32; ++kq) {
    float4 av[4], wv[2];
#pragma unroll
    for (int ri = 0; ri < 4; ++ri)
      av[ri] = *(const float4*)&As[ty * 4 + ri][kq * 4];
#pragma unroll
    for (int ci = 0; ci < 2; ++ci)
      wv[ci] = *(const float4*)&Ws[ci * 32 + tx][kq * 4];
#pragma unroll
    for (int ri = 0; ri < 4; ++ri)
#pragma unroll
      for (int ci = 0; ci < 2; ++ci) {
        acc[ri][ci] += av[ri].x * wv[ci].x + av[ri].y * wv[ci].y +
                       av[ri].z * wv[ci].z + av[ri].w * wv[ci].w;
      }
  }
#pragma unroll
  for (int ri = 0; ri < 4; ++ri) {
    int r = r0 + ty * 4 + ri;
    if (r < rows) {
#pragma unroll
      for (int ci = 0; ci < 2; ++ci)
        storeZ(&C[(size_t)r * D + jb + ci * 32 + tx], acc[ri][ci]);
    }
  }
}

// ---------------- per-node scalars: zs = z.a[0:128], zd = z.a[128:256] -----
template <typename ZT>
__global__ void node_scalars_kernel(const ZT* __restrict__ z,
                                    const float* __restrict__ a,
                                    float* __restrict__ zs,
                                    float* __restrict__ zd, int n) {
  int node = blockIdx.x * 4 + (threadIdx.x >> 6);
  if (node >= n) return;
  int lane = threadIdx.x & 63;
  float2 zv = loadZ2(&z[(size_t)node * D + lane * 2]);
  float2 a1 = *(const float2*)&a[lane * 2];
  float2 a2 = *(const float2*)&a[D + lane * 2];
  float ps = zv.x * a1.x + zv.y * a1.y;
  float pd = zv.x * a2.x + zv.y * a2.y;
  for (int o = 32; o; o >>= 1) {
    ps += __shfl_xor(ps, o);
    pd += __shfl_xor(pd, o);
  }
  if (lane == 0) {
    zs[node] = ps;
    zd[node] = pd;
  }
}

// ---------------- CSR build -------------------------------------------------
__global__ void zero_int_kernel(int* __restrict__ p, int n) {
  int i = blockIdx.x * 256 + threadIdx.x;
  if (i < n) p[i] = 0;
}

__global__ void count_kernel(const int* __restrict__ dst, int* __restrict__ cnt,
                             int E) {
  int i = blockIdx.x * 256 + threadIdx.x;
  if (i < E) atomicAdd(&cnt[dst[i]], 1);
}

// single block, 1024 threads: exclusive scan of cnt[0..n) -> offs, cursor
__global__ __launch_bounds__(1024) void scan_kernel(
    const int* __restrict__ cnt, int* __restrict__ offs,
    int* __restrict__ cursor, int n, int total) {
  __shared__ int sm[1024];
  const int t = threadIdx.x;
  const int chunk = (n + 1023) >> 10;
  const int b = t * chunk;
  const int e = min(b + chunk, n);
  int s = 0;
  for (int i = b; i < e; ++i) s += cnt[i];
  sm[t] = s;
  __syncthreads();
  for (int off = 1; off < 1024; off <<= 1) {
    int v = (t >= off) ? sm[t - off] : 0;
    __syncthreads();
    sm[t] += v;
    __syncthreads();
  }
  int run = sm[t] - s;
  for (int i = b; i < e; ++i) {
    int c = cnt[i];
    offs[i] = run;
    cursor[i] = run;
    run += c;
  }
  if (t == 0) offs[n] = total;
}

// scatter + fused edge-logit compute: csr_e[p] = lrelu(zs[src]+zd[dst]+d*vc)
__global__ void scatter_kernel(const int* __restrict__ src,
                               const int* __restrict__ dst,
                               const float* __restrict__ dE,
                               const float* __restrict__ zs,
                               const float* __restrict__ zd,
                               const float* __restrict__ V,
                               const float* __restrict__ a,
                               int* __restrict__ cursor,
                               int* __restrict__ csr_src,
                               float* __restrict__ csr_e, int E) {
  int i = blockIdx.x * 256 + threadIdx.x;
  if (i < E) {
    int di = dst[i];
    int si = src[i];
    int p = atomicAdd(&cursor[di], 1);
    float vc = V[0] * a[2 * D];
    csr_src[p] = si;
    csr_e[p] = lrelu(zs[si] + zd[di] + dE[i] * vc);
  }
}

// ---------------- per-dst: softmax + weighted accumulate -------------------
// one 64-lane wave per dst node; 4 waves per block. out row holds zi on
// entry and is updated in place.
template <typename ZT>
__global__ __launch_bounds__(256) void gat_perdst(
    const ZT* __restrict__ z, const int* __restrict__ csr_src,
    const float* __restrict__ csr_e, const int* __restrict__ offs,
    float* __restrict__ out, int nd) {
  int n = blockIdx.x * 4 + (threadIdx.x >> 6);
  if (n >= nd) return;
  int lane = threadIdx.x & 63;
  int beg = offs[n], end = offs[n + 1];

  // phase 1: segment max (lanes parallel over edges)
  float m = -INFINITY;
  for (int j = beg + lane; j < end; j += 64) m = fmaxf(m, csr_e[j]);
  for (int o = 32; o; o >>= 1) m = fmaxf(m, __shfl_xor(m, o));

  // phase 2: sum + weighted row accumulate (sequential over edges, lanes
  // cover the 128-wide feature dim as float2)
  float s = 0.f;
  float2 acc = make_float2(0.f, 0.f);
  for (int j = beg; j < end; ++j) {
    int srcj = csr_src[j];
    float w = __expf(csr_e[j] - m);
    s += w;
    float2 zv = loadZ2(&z[(size_t)srcj * D + lane * 2]);
    acc.x += w * zv.x;
    acc.y += w * zv.y;
  }
  float inv = (s > 0.f) ? 1.f / s : 0.f;
  float2 ziv = *(const float2*)&out[(size_t)n * D + lane * 2];
  float2 o2;
  o2.x = fmaxf(ziv.x + acc.x * inv, 0.f);
  o2.y = fmaxf(ziv.y + acc.y * inv, 0.f);
  *(float2*)&out[(size_t)n * D + lane * 2] = o2;
}

// ---------------------------------------------------------------------------
template <typename ZT>
static void run_layer(const float* h, int Nsrc, const float* dE,
                      const int* src, const int* dst, int nd, int E,
                      const float* W, const float* U, const float* V,
                      const float* a, ZT* z, float* zs, float* zd, int* offs,
                      int* cnt, int* cursor, int* csr_src, float* csr_e,
                      float* out, hipStream_t stream) {
  dim3 gz((Nsrc + 31) / 32, 2);
  gemm_rowdot<ZT><<<gz, 256, 0, stream>>>(h, W, z, Nsrc);
  // zi straight into the output buffer (updated in place by gat_perdst)
  dim3 gzi((nd + 31) / 32, 2);
  gemm_rowdot<float><<<gzi, 256, 0, stream>>>(h, U, out, nd);
  node_scalars_kernel<ZT><<<(Nsrc + 3) / 4, 256, 0, stream>>>(z, a, zs, zd,
                                                              Nsrc);
  zero_int_kernel<<<(nd + 255) / 256, 256, 0, stream>>>(cnt, nd);
  count_kernel<<<(E + 255) / 256, 256, 0, stream>>>(dst, cnt, E);
  scan_kernel<<<1, 1024, 0, stream>>>(cnt, offs, cursor, nd, E);
  scatter_kernel<<<(E + 255) / 256, 256, 0, stream>>>(
      src, dst, dE, zs, zd, V, a, cursor, csr_src, csr_e, E);
  gat_perdst<ZT><<<(nd + 3) / 4, 256, 0, stream>>>(z, csr_src, csr_e, offs,
                                                   out, nd);
}

extern "C" void kernel_launch(void* const* d_in, const int* in_sizes, int n_in,
                              void* d_out, int out_size, void* d_ws,
                              size_t ws_size, hipStream_t stream) {
  const float* attr = (const float*)d_in[0];
  const float* d0 = (const float*)d_in[1];
  const float* d1 = (const float*)d_in[2];
  const int* src0 = (const int*)d_in[3];
  const int* dst0 = (const int*)d_in[4];
  const int* src1 = (const int*)d_in[5];
  const int* dst1 = (const int*)d_in[6];
  const float* W0 = (const float*)d_in[9];
  const float* U0 = (const float*)d_in[10];
  const float* V0 = (const float*)d_in[11];
  const float* a0 = (const float*)d_in[12];
  const float* W1 = (const float*)d_in[13];
  const float* U1 = (const float*)d_in[14];
  const float* V1 = (const float*)d_in[15];
  const float* a1 = (const float*)d_in[16];

  const int N0 = in_sizes[0] / D;  // 100000
  const int E0 = in_sizes[1];      // 640000
  const int E1 = in_sizes[2];      // 320000
  const int ND0 = 40000;
  const int ND1 = 20000;

  char* p = (char*)d_ws;
  auto alloc = [&](size_t bytes) {
    char* q = p;
    p += (bytes + 255) & ~(size_t)255;
    return q;
  };
  // common small buffers
  float* h1;
  float* zs;
  float* zd;
  int* offs;
  int* cnt;
  int* cursor;
  int* csr_src;
  float* csr_e;
  auto carve_common = [&]() {
    h1 = (float*)alloc((size_t)ND0 * D * 4);
    zs = (float*)alloc((size_t)N0 * 4);
    zd = (float*)alloc((size_t)N0 * 4);
    offs = (int*)alloc((size_t)(ND0 + 1) * 4);
    cnt = (int*)alloc((size_t)ND0 * 4);
    cursor = (int*)alloc((size_t)ND0 * 4);
    csr_src = (int*)alloc((size_t)E0 * 4);
    csr_e = (float*)alloc((size_t)E0 * 4);
  };

  float* out = (float*)d_out;
  (void)n_in;
  (void)out_size;

  // Tier A needs ~78.1 MB (f32 z); tier B ~52.5 MB (bf16 z).
  if (ws_size >= (size_t)82 * 1024 * 1024) {
    float* z = (float*)alloc((size_t)N0 * D * 4);
    carve_common();
    run_layer<float>(attr, N0, d0, src0, dst0, ND0, E0, W0, U0, V0, a0, z, zs,
                     zd, offs, cnt, cursor, csr_src, csr_e, h1, stream);
    run_layer<float>(h1, ND0, d1, src1, dst1, ND1, E1, W1, U1, V1, a1, z, zs,
                     zd, offs, cnt, cursor, csr_src, csr_e, out, stream);
  } else {
    unsigned short* z = (unsigned short*)alloc((size_t)N0 * D * 2);
    carve_common();
    run_layer<unsigned short>(attr, N0, d0, src0, dst0, ND0, E0, W0, U0, V0,
                              a0, z, zs, zd, offs, cnt, cursor, csr_src, csr_e,
                              h1, stream);
    run_layer<unsigned short>(h1, ND0, d1, src1, dst1, ND1, E1, W1, U1, V1, a1,
                              z, zs, zd, offs, cnt, cursor, csr_src, csr_e, out,
                              stream);
  }
}

// Round 3
// 401.922 us; speedup vs baseline: 1.2886x; 1.2886x over previous
//
#include <hip/hip_runtime.h>
#include <math.h>

// ---------------------------------------------------------------------------
// 2-layer GAT on MI355X.
// Layer: z = h@W.T ; zi = h@U.T ; e = lrelu(zs[src]+zd[dst]+d*V*a[2D])
//        segment-softmax over dst ; out = relu(zi + sum(alpha*z[src]))
// R2 -> R3: the single-block scan_kernel was 2x91us (35% of runtime,
// occupancy 0.14%). Replaced with a 3-kernel hierarchical scan.
// ---------------------------------------------------------------------------

#define D 128

static __device__ __forceinline__ float lrelu(float x) {
  return x >= 0.f ? x : 0.01f * x;
}

// ---- z-storage abstraction (float or bf16-in-ushort) ----------------------
static __device__ __forceinline__ void storeZ(float* p, float v) { *p = v; }
static __device__ __forceinline__ void storeZ(unsigned short* p, float v) {
  unsigned int u = __float_as_uint(v);
  u += 0x7fffu + ((u >> 16) & 1u);  // round-to-nearest-even
  *p = (unsigned short)(u >> 16);
}
static __device__ __forceinline__ float2 loadZ2(const float* p) {
  return *(const float2*)p;
}
static __device__ __forceinline__ float2 loadZ2(const unsigned short* p) {
  ushort2 t = *(const ushort2*)p;
  return make_float2(__uint_as_float((unsigned int)t.x << 16),
                     __uint_as_float((unsigned int)t.y << 16));
}

// ---------------- GEMM: C[r][j] = sum_k A[r][k] * B[j][k] ------------------
template <typename ZT>
__global__ __launch_bounds__(256) void gemm_rowdot(
    const float* __restrict__ A, const float* __restrict__ B,
    ZT* __restrict__ C, int rows) {
  __shared__ float As[32][132];
  __shared__ float Ws[64][132];
  const int t = threadIdx.x;
  const int r0 = blockIdx.x * 32;
  const int jb = blockIdx.y * 64;

#pragma unroll
  for (int i = 0; i < 4; ++i) {
    int v = t + i * 256;
    int row = v >> 5, kq = v & 31;
    float4 val = make_float4(0.f, 0.f, 0.f, 0.f);
    if (r0 + row < rows)
      val = *(const float4*)&A[(size_t)(r0 + row) * D + kq * 4];
    *(float4*)&As[row][kq * 4] = val;
  }
#pragma unroll
  for (int i = 0; i < 8; ++i) {
    int v = t + i * 256;
    int row = v >> 5, kq = v & 31;
    float4 val = *(const float4*)&B[(size_t)(jb + row) * D + kq * 4];
    *(float4*)&Ws[row][kq * 4] = val;
  }
  __syncthreads();

  const int tx = t & 31, ty = t >> 5;
  float acc[4][2] = {};
#pragma unroll 8
  for (int kq = 0; kq < 32; ++kq) {
    float4 av[4], wv[2];
#pragma unroll
    for (int ri = 0; ri < 4; ++ri)
      av[ri] = *(const float4*)&As[ty * 4 + ri][kq * 4];
#pragma unroll
    for (int ci = 0; ci < 2; ++ci)
      wv[ci] = *(const float4*)&Ws[ci * 32 + tx][kq * 4];
#pragma unroll
    for (int ri = 0; ri < 4; ++ri)
#pragma unroll
      for (int ci = 0; ci < 2; ++ci) {
        acc[ri][ci] += av[ri].x * wv[ci].x + av[ri].y * wv[ci].y +
                       av[ri].z * wv[ci].z + av[ri].w * wv[ci].w;
      }
  }
#pragma unroll
  for (int ri = 0; ri < 4; ++ri) {
    int r = r0 + ty * 4 + ri;
    if (r < rows) {
#pragma unroll
      for (int ci = 0; ci < 2; ++ci)
        storeZ(&C[(size_t)r * D + jb + ci * 32 + tx], acc[ri][ci]);
    }
  }
}

// ---------------- per-node scalars: zs = z.a[0:128], zd = z.a[128:256] -----
template <typename ZT>
__global__ void node_scalars_kernel(const ZT* __restrict__ z,
                                    const float* __restrict__ a,
                                    float* __restrict__ zs,
                                    float* __restrict__ zd, int n) {
  int node = blockIdx.x * 4 + (threadIdx.x >> 6);
  if (node >= n) return;
  int lane = threadIdx.x & 63;
  float2 zv = loadZ2(&z[(size_t)node * D + lane * 2]);
  float2 a1 = *(const float2*)&a[lane * 2];
  float2 a2 = *(const float2*)&a[D + lane * 2];
  float ps = zv.x * a1.x + zv.y * a1.y;
  float pd = zv.x * a2.x + zv.y * a2.y;
  for (int o = 32; o; o >>= 1) {
    ps += __shfl_xor(ps, o);
    pd += __shfl_xor(pd, o);
  }
  if (lane == 0) {
    zs[node] = ps;
    zd[node] = pd;
  }
}

// ---------------- CSR build -------------------------------------------------
__global__ void zero_int_kernel(int* __restrict__ p, int n) {
  int i = blockIdx.x * 256 + threadIdx.x;
  if (i < n) p[i] = 0;
}

__global__ void count_kernel(const int* __restrict__ dst, int* __restrict__ cnt,
                             int E) {
  int i = blockIdx.x * 256 + threadIdx.x;
  if (i < E) atomicAdd(&cnt[dst[i]], 1);
}

// --- hierarchical exclusive scan: partial sums -> top scan -> final --------
// A: per-1024-chunk sums (grid = ceil(n/1024), 256 thr)
__global__ __launch_bounds__(256) void scan_partial(const int* __restrict__ cnt,
                                                    int* __restrict__ part,
                                                    int n) {
  __shared__ int sm[4];
  int base = blockIdx.x * 1024;
  int t = threadIdx.x;
  int s = 0;
#pragma unroll
  for (int i = 0; i < 4; ++i) {
    int idx = base + t + i * 256;
    s += (idx < n) ? cnt[idx] : 0;
  }
  for (int o = 32; o; o >>= 1) s += __shfl_xor(s, o);
  if ((t & 63) == 0) sm[t >> 6] = s;
  __syncthreads();
  if (t == 0) part[blockIdx.x] = sm[0] + sm[1] + sm[2] + sm[3];
}

// B: exclusive scan of part[0..nb), nb <= 64, one wave
__global__ void scan_top(int* __restrict__ part, int nb) {
  int t = threadIdx.x;
  int orig = (t < nb) ? part[t] : 0;
  int v = orig;
#pragma unroll
  for (int o = 1; o < 64; o <<= 1) {
    int u = __shfl_up(v, o);
    if (t >= o) v += u;
  }
  if (t < nb) part[t] = v - orig;
}

// C: per-chunk exclusive scan + add block offset; write offs & cursor
__global__ __launch_bounds__(256) void scan_final(
    const int* __restrict__ cnt, const int* __restrict__ part,
    int* __restrict__ offs, int* __restrict__ cursor, int n, int total) {
  __shared__ int sm[4];
  int base = blockIdx.x * 1024;
  int t = threadIdx.x;
  int idx = base + t * 4;
  int c0 = (idx + 0 < n) ? cnt[idx + 0] : 0;
  int c1 = (idx + 1 < n) ? cnt[idx + 1] : 0;
  int c2 = (idx + 2 < n) ? cnt[idx + 2] : 0;
  int c3 = (idx + 3 < n) ? cnt[idx + 3] : 0;
  int ts = c0 + c1 + c2 + c3;
  int v = ts;
#pragma unroll
  for (int o = 1; o < 64; o <<= 1) {
    int u = __shfl_up(v, o);
    if ((t & 63) >= o) v += u;
  }
  if ((t & 63) == 63) sm[t >> 6] = v;
  __syncthreads();
  int w = t >> 6;
  int waveoff = 0;
  if (w > 0) waveoff += sm[0];
  if (w > 1) waveoff += sm[1];
  if (w > 2) waveoff += sm[2];
  int run = v - ts + waveoff + part[blockIdx.x];
  if (idx + 0 < n) { offs[idx + 0] = run; cursor[idx + 0] = run; run += c0; }
  if (idx + 1 < n) { offs[idx + 1] = run; cursor[idx + 1] = run; run += c1; }
  if (idx + 2 < n) { offs[idx + 2] = run; cursor[idx + 2] = run; run += c2; }
  if (idx + 3 < n) { offs[idx + 3] = run; cursor[idx + 3] = run; run += c3; }
  if (blockIdx.x == 0 && t == 0) offs[n] = total;
}

// scatter + fused edge-logit compute: csr_e[p] = lrelu(zs[src]+zd[dst]+d*vc)
__global__ void scatter_kernel(const int* __restrict__ src,
                               const int* __restrict__ dst,
                               const float* __restrict__ dE,
                               const float* __restrict__ zs,
                               const float* __restrict__ zd,
                               const float* __restrict__ V,
                               const float* __restrict__ a,
                               int* __restrict__ cursor,
                               int* __restrict__ csr_src,
                               float* __restrict__ csr_e, int E) {
  int i = blockIdx.x * 256 + threadIdx.x;
  if (i < E) {
    int di = dst[i];
    int si = src[i];
    int p = atomicAdd(&cursor[di], 1);
    float vc = V[0] * a[2 * D];
    csr_src[p] = si;
    csr_e[p] = lrelu(zs[si] + zd[di] + dE[i] * vc);
  }
}

// ---------------- per-dst: softmax + weighted accumulate -------------------
template <typename ZT>
__global__ __launch_bounds__(256) void gat_perdst(
    const ZT* __restrict__ z, const int* __restrict__ csr_src,
    const float* __restrict__ csr_e, const int* __restrict__ offs,
    float* __restrict__ out, int nd) {
  int n = blockIdx.x * 4 + (threadIdx.x >> 6);
  if (n >= nd) return;
  int lane = threadIdx.x & 63;
  int beg = offs[n], end = offs[n + 1];

  float m = -INFINITY;
  for (int j = beg + lane; j < end; j += 64) m = fmaxf(m, csr_e[j]);
  for (int o = 32; o; o >>= 1) m = fmaxf(m, __shfl_xor(m, o));

  float s = 0.f;
  float2 acc = make_float2(0.f, 0.f);
  for (int j = beg; j < end; ++j) {
    int srcj = csr_src[j];
    float w = __expf(csr_e[j] - m);
    s += w;
    float2 zv = loadZ2(&z[(size_t)srcj * D + lane * 2]);
    acc.x += w * zv.x;
    acc.y += w * zv.y;
  }
  float inv = (s > 0.f) ? 1.f / s : 0.f;
  float2 ziv = *(const float2*)&out[(size_t)n * D + lane * 2];
  float2 o2;
  o2.x = fmaxf(ziv.x + acc.x * inv, 0.f);
  o2.y = fmaxf(ziv.y + acc.y * inv, 0.f);
  *(float2*)&out[(size_t)n * D + lane * 2] = o2;
}

// ---------------------------------------------------------------------------
template <typename ZT>
static void run_layer(const float* h, int Nsrc, const float* dE,
                      const int* src, const int* dst, int nd, int E,
                      const float* W, const float* U, const float* V,
                      const float* a, ZT* z, float* zs, float* zd, int* offs,
                      int* cnt, int* cursor, int* part, int* csr_src,
                      float* csr_e, float* out, hipStream_t stream) {
  dim3 gz((Nsrc + 31) / 32, 2);
  gemm_rowdot<ZT><<<gz, 256, 0, stream>>>(h, W, z, Nsrc);
  dim3 gzi((nd + 31) / 32, 2);
  gemm_rowdot<float><<<gzi, 256, 0, stream>>>(h, U, out, nd);
  node_scalars_kernel<ZT><<<(Nsrc + 3) / 4, 256, 0, stream>>>(z, a, zs, zd,
                                                              Nsrc);
  zero_int_kernel<<<(nd + 255) / 256, 256, 0, stream>>>(cnt, nd);
  count_kernel<<<(E + 255) / 256, 256, 0, stream>>>(dst, cnt, E);
  int nb = (nd + 1023) / 1024;  // <= 40 (fits one wave in scan_top)
  scan_partial<<<nb, 256, 0, stream>>>(cnt, part, nd);
  scan_top<<<1, 64, 0, stream>>>(part, nb);
  scan_final<<<nb, 256, 0, stream>>>(cnt, part, offs, cursor, nd, E);
  scatter_kernel<<<(E + 255) / 256, 256, 0, stream>>>(
      src, dst, dE, zs, zd, V, a, cursor, csr_src, csr_e, E);
  gat_perdst<ZT><<<(nd + 3) / 4, 256, 0, stream>>>(z, csr_src, csr_e, offs,
                                                   out, nd);
}

extern "C" void kernel_launch(void* const* d_in, const int* in_sizes, int n_in,
                              void* d_out, int out_size, void* d_ws,
                              size_t ws_size, hipStream_t stream) {
  const float* attr = (const float*)d_in[0];
  const float* d0 = (const float*)d_in[1];
  const float* d1 = (const float*)d_in[2];
  const int* src0 = (const int*)d_in[3];
  const int* dst0 = (const int*)d_in[4];
  const int* src1 = (const int*)d_in[5];
  const int* dst1 = (const int*)d_in[6];
  const float* W0 = (const float*)d_in[9];
  const float* U0 = (const float*)d_in[10];
  const float* V0 = (const float*)d_in[11];
  const float* a0 = (const float*)d_in[12];
  const float* W1 = (const float*)d_in[13];
  const float* U1 = (const float*)d_in[14];
  const float* V1 = (const float*)d_in[15];
  const float* a1 = (const float*)d_in[16];

  const int N0 = in_sizes[0] / D;  // 100000
  const int E0 = in_sizes[1];      // 640000
  const int E1 = in_sizes[2];      // 320000
  const int ND0 = 40000;
  const int ND1 = 20000;

  char* p = (char*)d_ws;
  auto alloc = [&](size_t bytes) {
    char* q = p;
    p += (bytes + 255) & ~(size_t)255;
    return q;
  };
  float* h1;
  float* zs;
  float* zd;
  int* offs;
  int* cnt;
  int* cursor;
  int* part;
  int* csr_src;
  float* csr_e;
  auto carve_common = [&]() {
    h1 = (float*)alloc((size_t)ND0 * D * 4);
    zs = (float*)alloc((size_t)N0 * 4);
    zd = (float*)alloc((size_t)N0 * 4);
    offs = (int*)alloc((size_t)(ND0 + 1) * 4);
    cnt = (int*)alloc((size_t)ND0 * 4);
    cursor = (int*)alloc((size_t)ND0 * 4);
    part = (int*)alloc((size_t)64 * 4);
    csr_src = (int*)alloc((size_t)E0 * 4);
    csr_e = (float*)alloc((size_t)E0 * 4);
  };

  float* out = (float*)d_out;
  (void)n_in;
  (void)out_size;

  if (ws_size >= (size_t)82 * 1024 * 1024) {
    float* z = (float*)alloc((size_t)N0 * D * 4);
    carve_common();
    run_layer<float>(attr, N0, d0, src0, dst0, ND0, E0, W0, U0, V0, a0, z, zs,
                     zd, offs, cnt, cursor, part, csr_src, csr_e, h1, stream);
    run_layer<float>(h1, ND0, d1, src1, dst1, ND1, E1, W1, U1, V1, a1, z, zs,
                     zd, offs, cnt, cursor, part, csr_src, csr_e, out, stream);
  } else {
    unsigned short* z = (unsigned short*)alloc((size_t)N0 * D * 2);
    carve_common();
    run_layer<unsigned short>(attr, N0, d0, src0, dst0, ND0, E0, W0, U0, V0,
                              a0, z, zs, zd, offs, cnt, cursor, part, csr_src,
                              csr_e, h1, stream);
    run_layer<unsigned short>(h1, ND0, d1, src1, dst1, ND1, E1, W1, U1, V1, a1,
                              z, zs, zd, offs, cnt, cursor, part, csr_src,
                              csr_e, out, stream);
  }
}

// Round 4
// 321.340 us; speedup vs baseline: 1.6117x; 1.2508x over previous
//
#include <hip/hip_runtime.h>
#include <math.h>

// ---------------------------------------------------------------------------
// 2-layer GAT on MI355X.
// R3 -> R4: f32 vector GEMM (80us, MfmaUtil=0, VALUBusy 64%) replaced with
// bf16 MFMA GEMM (16x16x32), W pre-converted to bf16 (L1-resident, fragments
// loaded straight from global -- no LDS, no barriers). zs/zd fused into the
// z-GEMM epilogue (node_scalars pass deleted).
// ---------------------------------------------------------------------------

#define D 128

typedef __bf16 bf16x8 __attribute__((ext_vector_type(8)));
typedef float f32x4 __attribute__((ext_vector_type(4)));

static __device__ __forceinline__ float lrelu(float x) {
  return x >= 0.f ? x : 0.01f * x;
}

// ---- output-store abstraction (float or bf16-bits-in-ushort) --------------
static __device__ __forceinline__ void storeOut(float* p, float v) { *p = v; }
static __device__ __forceinline__ void storeOut(unsigned short* p, float v) {
  unsigned int u = __float_as_uint(v);
  u += 0x7fffu + ((u >> 16) & 1u);  // round-to-nearest-even
  *p = (unsigned short)(u >> 16);
}
static __device__ __forceinline__ float2 loadZ2(const unsigned short* p) {
  ushort2 t = *(const ushort2*)p;
  return make_float2(__uint_as_float((unsigned int)t.x << 16),
                     __uint_as_float((unsigned int)t.y << 16));
}

// ---- weight f32 -> bf16 (4 matrices of 128x128 in one launch) -------------
__global__ __launch_bounds__(256) void cvt4_kernel(
    const float* __restrict__ s0, const float* __restrict__ s1,
    const float* __restrict__ s2, const float* __restrict__ s3,
    __bf16* __restrict__ dst) {
  int idx = blockIdx.x * 256 + threadIdx.x;  // 0..65535
  const float* s = (idx < 16384) ? s0
                   : (idx < 32768) ? s1
                   : (idx < 49152) ? s2 : s3;
  dst[idx] = (__bf16)s[idx & 16383];
}

// ---------------- MFMA GEMM: C[r][j] = sum_k A[r][k] * Wb[j][k] ------------
// A: [rows][128] f32 (converted to bf16 in-register), Wb: [128][128] bf16.
// One wave = 16 rows x 128 cols; block = 4 waves = 64 rows. No LDS.
// Fragment layout (mfma_f32_16x16x32_bf16, m89-verified):
//   A: lane l holds A[r0 + (l&15)][k0 + (l>>4)*8 + i], i=0..7
//   B: lane l holds Wb[j0 + (l&15)][k0 + (l>>4)*8 + i]   (B[k][n] = Wb[n][k])
//   C: col = l&15, row = (l>>4)*4 + reg
template <typename OutT, bool WITH_SCAL>
__global__ __launch_bounds__(256) void gemm_mfma(
    const float* __restrict__ A, const __bf16* __restrict__ Wb,
    OutT* __restrict__ C, const float* __restrict__ a,
    float* __restrict__ zs, float* __restrict__ zd, int rows) {
  const int wave = threadIdx.x >> 6;
  const int lane = threadIdx.x & 63;
  const int r0 = (blockIdx.x * 4 + wave) * 16;
  if (r0 >= rows) return;
  const int lm = lane & 15;
  const int lk = lane >> 4;

  f32x4 acc[8];
#pragma unroll
  for (int t = 0; t < 8; ++t) acc[t] = (f32x4){0.f, 0.f, 0.f, 0.f};

  const float* arow = A + (size_t)(r0 + lm) * D + lk * 8;
#pragma unroll
  for (int kt = 0; kt < 4; ++kt) {
    float4 av0 = *(const float4*)(arow + kt * 32 + 0);
    float4 av1 = *(const float4*)(arow + kt * 32 + 4);
    bf16x8 af;
    af[0] = (__bf16)av0.x; af[1] = (__bf16)av0.y;
    af[2] = (__bf16)av0.z; af[3] = (__bf16)av0.w;
    af[4] = (__bf16)av1.x; af[5] = (__bf16)av1.y;
    af[6] = (__bf16)av1.z; af[7] = (__bf16)av1.w;
#pragma unroll
    for (int t = 0; t < 8; ++t) {
      const __bf16* bp = Wb + (size_t)(t * 16 + lm) * D + kt * 32 + lk * 8;
      bf16x8 bf = *(const bf16x8*)bp;
      acc[t] = __builtin_amdgcn_mfma_f32_16x16x32_bf16(af, bf, acc[t], 0, 0, 0);
    }
  }

  // store C: row = r0 + lk*4 + rr, col = t*16 + lm
#pragma unroll
  for (int t = 0; t < 8; ++t) {
#pragma unroll
    for (int rr = 0; rr < 4; ++rr) {
      storeOut(&C[(size_t)(r0 + lk * 4 + rr) * D + t * 16 + lm], acc[t][rr]);
    }
  }

  if constexpr (WITH_SCAL) {
    float a1v[8], a2v[8];
#pragma unroll
    for (int t = 0; t < 8; ++t) {
      a1v[t] = a[t * 16 + lm];
      a2v[t] = a[D + t * 16 + lm];
    }
#pragma unroll
    for (int rr = 0; rr < 4; ++rr) {
      float p1 = 0.f, p2 = 0.f;
#pragma unroll
      for (int t = 0; t < 8; ++t) {
        p1 += acc[t][rr] * a1v[t];
        p2 += acc[t][rr] * a2v[t];
      }
#pragma unroll
      for (int o = 1; o < 16; o <<= 1) {
        p1 += __shfl_xor(p1, o);
        p2 += __shfl_xor(p2, o);
      }
      if (lm == 0) {
        zs[r0 + lk * 4 + rr] = p1;
        zd[r0 + lk * 4 + rr] = p2;
      }
    }
  }
}

// ---------------- CSR build -------------------------------------------------
__global__ void zero_int_kernel(int* __restrict__ p, int n) {
  int i = blockIdx.x * 256 + threadIdx.x;
  if (i < n) p[i] = 0;
}

__global__ void count_kernel(const int* __restrict__ dst, int* __restrict__ cnt,
                             int E) {
  int i = blockIdx.x * 256 + threadIdx.x;
  if (i < E) atomicAdd(&cnt[dst[i]], 1);
}

// A: per-1024-chunk sums
__global__ __launch_bounds__(256) void scan_partial(const int* __restrict__ cnt,
                                                    int* __restrict__ part,
                                                    int n) {
  __shared__ int sm[4];
  int base = blockIdx.x * 1024;
  int t = threadIdx.x;
  int s = 0;
#pragma unroll
  for (int i = 0; i < 4; ++i) {
    int idx = base + t + i * 256;
    s += (idx < n) ? cnt[idx] : 0;
  }
  for (int o = 32; o; o >>= 1) s += __shfl_xor(s, o);
  if ((t & 63) == 0) sm[t >> 6] = s;
  __syncthreads();
  if (t == 0) part[blockIdx.x] = sm[0] + sm[1] + sm[2] + sm[3];
}

// B: exclusive scan of part[0..nb), nb <= 64, one wave
__global__ void scan_top(int* __restrict__ part, int nb) {
  int t = threadIdx.x;
  int orig = (t < nb) ? part[t] : 0;
  int v = orig;
#pragma unroll
  for (int o = 1; o < 64; o <<= 1) {
    int u = __shfl_up(v, o);
    if (t >= o) v += u;
  }
  if (t < nb) part[t] = v - orig;
}

// C: per-chunk exclusive scan + block offset; write offs & cursor
__global__ __launch_bounds__(256) void scan_final(
    const int* __restrict__ cnt, const int* __restrict__ part,
    int* __restrict__ offs, int* __restrict__ cursor, int n, int total) {
  __shared__ int sm[4];
  int base = blockIdx.x * 1024;
  int t = threadIdx.x;
  int idx = base + t * 4;
  int c0 = (idx + 0 < n) ? cnt[idx + 0] : 0;
  int c1 = (idx + 1 < n) ? cnt[idx + 1] : 0;
  int c2 = (idx + 2 < n) ? cnt[idx + 2] : 0;
  int c3 = (idx + 3 < n) ? cnt[idx + 3] : 0;
  int ts = c0 + c1 + c2 + c3;
  int v = ts;
#pragma unroll
  for (int o = 1; o < 64; o <<= 1) {
    int u = __shfl_up(v, o);
    if ((t & 63) >= o) v += u;
  }
  if ((t & 63) == 63) sm[t >> 6] = v;
  __syncthreads();
  int w = t >> 6;
  int waveoff = 0;
  if (w > 0) waveoff += sm[0];
  if (w > 1) waveoff += sm[1];
  if (w > 2) waveoff += sm[2];
  int run = v - ts + waveoff + part[blockIdx.x];
  if (idx + 0 < n) { offs[idx + 0] = run; cursor[idx + 0] = run; run += c0; }
  if (idx + 1 < n) { offs[idx + 1] = run; cursor[idx + 1] = run; run += c1; }
  if (idx + 2 < n) { offs[idx + 2] = run; cursor[idx + 2] = run; run += c2; }
  if (idx + 3 < n) { offs[idx + 3] = run; cursor[idx + 3] = run; run += c3; }
  if (blockIdx.x == 0 && t == 0) offs[n] = total;
}

// scatter + fused edge-logit: csr_e[p] = lrelu(zs[src]+zd[dst]+d*vc)
__global__ void scatter_kernel(const int* __restrict__ src,
                               const int* __restrict__ dst,
                               const float* __restrict__ dE,
                               const float* __restrict__ zs,
                               const float* __restrict__ zd,
                               const float* __restrict__ V,
                               const float* __restrict__ a,
                               int* __restrict__ cursor,
                               int* __restrict__ csr_src,
                               float* __restrict__ csr_e, int E) {
  int i = blockIdx.x * 256 + threadIdx.x;
  if (i < E) {
    int di = dst[i];
    int si = src[i];
    int p = atomicAdd(&cursor[di], 1);
    float vc = V[0] * a[2 * D];
    csr_src[p] = si;
    csr_e[p] = lrelu(zs[si] + zd[di] + dE[i] * vc);
  }
}

// ---------------- per-dst: softmax + weighted accumulate -------------------
__global__ __launch_bounds__(256) void gat_perdst(
    const unsigned short* __restrict__ z, const int* __restrict__ csr_src,
    const float* __restrict__ csr_e, const int* __restrict__ offs,
    float* __restrict__ out, int nd) {
  int n = blockIdx.x * 4 + (threadIdx.x >> 6);
  if (n >= nd) return;
  int lane = threadIdx.x & 63;
  int beg = offs[n], end = offs[n + 1];

  float m = -INFINITY;
  for (int j = beg + lane; j < end; j += 64) m = fmaxf(m, csr_e[j]);
  for (int o = 32; o; o >>= 1) m = fmaxf(m, __shfl_xor(m, o));

  float s = 0.f;
  float2 acc = make_float2(0.f, 0.f);
  for (int j = beg; j < end; ++j) {
    int srcj = csr_src[j];
    float w = __expf(csr_e[j] - m);
    s += w;
    float2 zv = loadZ2(&z[(size_t)srcj * D + lane * 2]);
    acc.x += w * zv.x;
    acc.y += w * zv.y;
  }
  float inv = (s > 0.f) ? 1.f / s : 0.f;
  float2 ziv = *(const float2*)&out[(size_t)n * D + lane * 2];
  float2 o2;
  o2.x = fmaxf(ziv.x + acc.x * inv, 0.f);
  o2.y = fmaxf(ziv.y + acc.y * inv, 0.f);
  *(float2*)&out[(size_t)n * D + lane * 2] = o2;
}

// ---------------------------------------------------------------------------
static void run_layer(const float* h, int Nsrc, const float* dE,
                      const int* src, const int* dst, int nd, int E,
                      const __bf16* Wb, const __bf16* Ub, const float* V,
                      const float* a, unsigned short* z, float* zs, float* zd,
                      int* offs, int* cnt, int* cursor, int* part,
                      int* csr_src, float* csr_e, float* out,
                      hipStream_t stream) {
  gemm_mfma<unsigned short, true><<<(Nsrc + 63) / 64, 256, 0, stream>>>(
      h, Wb, z, a, zs, zd, Nsrc);
  gemm_mfma<float, false><<<(nd + 63) / 64, 256, 0, stream>>>(
      h, Ub, out, nullptr, nullptr, nullptr, nd);
  zero_int_kernel<<<(nd + 255) / 256, 256, 0, stream>>>(cnt, nd);
  count_kernel<<<(E + 255) / 256, 256, 0, stream>>>(dst, cnt, E);
  int nb = (nd + 1023) / 1024;  // <= 40
  scan_partial<<<nb, 256, 0, stream>>>(cnt, part, nd);
  scan_top<<<1, 64, 0, stream>>>(part, nb);
  scan_final<<<nb, 256, 0, stream>>>(cnt, part, offs, cursor, nd, E);
  scatter_kernel<<<(E + 255) / 256, 256, 0, stream>>>(
      src, dst, dE, zs, zd, V, a, cursor, csr_src, csr_e, E);
  gat_perdst<<<(nd + 3) / 4, 256, 0, stream>>>(z, csr_src, csr_e, offs, out,
                                               nd);
}

extern "C" void kernel_launch(void* const* d_in, const int* in_sizes, int n_in,
                              void* d_out, int out_size, void* d_ws,
                              size_t ws_size, hipStream_t stream) {
  const float* attr = (const float*)d_in[0];
  const float* d0 = (const float*)d_in[1];
  const float* d1 = (const float*)d_in[2];
  const int* src0 = (const int*)d_in[3];
  const int* dst0 = (const int*)d_in[4];
  const int* src1 = (const int*)d_in[5];
  const int* dst1 = (const int*)d_in[6];
  const float* W0 = (const float*)d_in[9];
  const float* U0 = (const float*)d_in[10];
  const float* V0 = (const float*)d_in[11];
  const float* a0 = (const float*)d_in[12];
  const float* W1 = (const float*)d_in[13];
  const float* U1 = (const float*)d_in[14];
  const float* V1 = (const float*)d_in[15];
  const float* a1 = (const float*)d_in[16];

  const int N0 = in_sizes[0] / D;  // 100000
  const int E0 = in_sizes[1];      // 640000
  const int E1 = in_sizes[2];      // 320000
  const int ND0 = 40000;
  const int ND1 = 20000;

  char* p = (char*)d_ws;
  auto alloc = [&](size_t bytes) {
    char* q = p;
    p += (bytes + 255) & ~(size_t)255;
    return q;
  };
  unsigned short* z = (unsigned short*)alloc((size_t)N0 * D * 2);
  float* h1 = (float*)alloc((size_t)ND0 * D * 4);
  float* zs = (float*)alloc((size_t)N0 * 4);
  float* zd = (float*)alloc((size_t)N0 * 4);
  int* offs = (int*)alloc((size_t)(ND0 + 1) * 4);
  int* cnt = (int*)alloc((size_t)ND0 * 4);
  int* cursor = (int*)alloc((size_t)ND0 * 4);
  int* part = (int*)alloc((size_t)64 * 4);
  int* csr_src = (int*)alloc((size_t)E0 * 4);
  float* csr_e = (float*)alloc((size_t)E0 * 4);
  __bf16* wb = (__bf16*)alloc((size_t)4 * D * D * 2);  // W0,U0,W1,U1 bf16
  (void)n_in;
  (void)out_size;
  (void)ws_size;

  float* out = (float*)d_out;

  cvt4_kernel<<<256, 256, 0, stream>>>(W0, U0, W1, U1, wb);
  const __bf16* W0b = wb;
  const __bf16* U0b = wb + 16384;
  const __bf16* W1b = wb + 32768;
  const __bf16* U1b = wb + 49152;

  run_layer(attr, N0, d0, src0, dst0, ND0, E0, W0b, U0b, V0, a0, z, zs, zd,
            offs, cnt, cursor, part, csr_src, csr_e, h1, stream);
  run_layer(h1, ND0, d1, src1, dst1, ND1, E1, W1b, U1b, V1, a1, z, zs, zd,
            offs, cnt, cursor, part, csr_src, csr_e, out, stream);
}

// Round 5
// 269.980 us; speedup vs baseline: 1.9183x; 1.1902x over previous
//
#include <hip/hip_runtime.h>
#include <math.h>

// ---------------------------------------------------------------------------
// 2-layer GAT on MI355X.
// R4 -> R5: gat_perdst was latency-bound (72us, VALUBusy 29%): serial edge
// loop with a 2-deep dependent load chain per edge. Unrolled x8 with batched
// loads (8 idx/logit loads, then 8 independent z-row gathers, then VALU).
// ---------------------------------------------------------------------------

#define D 128

typedef __bf16 bf16x8 __attribute__((ext_vector_type(8)));
typedef float f32x4 __attribute__((ext_vector_type(4)));

static __device__ __forceinline__ float lrelu(float x) {
  return x >= 0.f ? x : 0.01f * x;
}

// ---- output-store abstraction (float or bf16-bits-in-ushort) --------------
static __device__ __forceinline__ void storeOut(float* p, float v) { *p = v; }
static __device__ __forceinline__ void storeOut(unsigned short* p, float v) {
  unsigned int u = __float_as_uint(v);
  u += 0x7fffu + ((u >> 16) & 1u);  // round-to-nearest-even
  *p = (unsigned short)(u >> 16);
}
static __device__ __forceinline__ float2 loadZ2(const unsigned short* p) {
  ushort2 t = *(const ushort2*)p;
  return make_float2(__uint_as_float((unsigned int)t.x << 16),
                     __uint_as_float((unsigned int)t.y << 16));
}

// ---- weight f32 -> bf16 (4 matrices of 128x128 in one launch) -------------
__global__ __launch_bounds__(256) void cvt4_kernel(
    const float* __restrict__ s0, const float* __restrict__ s1,
    const float* __restrict__ s2, const float* __restrict__ s3,
    __bf16* __restrict__ dst) {
  int idx = blockIdx.x * 256 + threadIdx.x;  // 0..65535
  const float* s = (idx < 16384) ? s0
                   : (idx < 32768) ? s1
                   : (idx < 49152) ? s2 : s3;
  dst[idx] = (__bf16)s[idx & 16383];
}

// ---------------- MFMA GEMM: C[r][j] = sum_k A[r][k] * Wb[j][k] ------------
// One wave = 16 rows x 128 cols; block = 4 waves = 64 rows. No LDS.
template <typename OutT, bool WITH_SCAL>
__global__ __launch_bounds__(256) void gemm_mfma(
    const float* __restrict__ A, const __bf16* __restrict__ Wb,
    OutT* __restrict__ C, const float* __restrict__ a,
    float* __restrict__ zs, float* __restrict__ zd, int rows) {
  const int wave = threadIdx.x >> 6;
  const int lane = threadIdx.x & 63;
  const int r0 = (blockIdx.x * 4 + wave) * 16;
  if (r0 >= rows) return;
  const int lm = lane & 15;
  const int lk = lane >> 4;

  f32x4 acc[8];
#pragma unroll
  for (int t = 0; t < 8; ++t) acc[t] = (f32x4){0.f, 0.f, 0.f, 0.f};

  const float* arow = A + (size_t)(r0 + lm) * D + lk * 8;
#pragma unroll
  for (int kt = 0; kt < 4; ++kt) {
    float4 av0 = *(const float4*)(arow + kt * 32 + 0);
    float4 av1 = *(const float4*)(arow + kt * 32 + 4);
    bf16x8 af;
    af[0] = (__bf16)av0.x; af[1] = (__bf16)av0.y;
    af[2] = (__bf16)av0.z; af[3] = (__bf16)av0.w;
    af[4] = (__bf16)av1.x; af[5] = (__bf16)av1.y;
    af[6] = (__bf16)av1.z; af[7] = (__bf16)av1.w;
#pragma unroll
    for (int t = 0; t < 8; ++t) {
      const __bf16* bp = Wb + (size_t)(t * 16 + lm) * D + kt * 32 + lk * 8;
      bf16x8 bf = *(const bf16x8*)bp;
      acc[t] = __builtin_amdgcn_mfma_f32_16x16x32_bf16(af, bf, acc[t], 0, 0, 0);
    }
  }

#pragma unroll
  for (int t = 0; t < 8; ++t) {
#pragma unroll
    for (int rr = 0; rr < 4; ++rr) {
      storeOut(&C[(size_t)(r0 + lk * 4 + rr) * D + t * 16 + lm], acc[t][rr]);
    }
  }

  if constexpr (WITH_SCAL) {
    float a1v[8], a2v[8];
#pragma unroll
    for (int t = 0; t < 8; ++t) {
      a1v[t] = a[t * 16 + lm];
      a2v[t] = a[D + t * 16 + lm];
    }
#pragma unroll
    for (int rr = 0; rr < 4; ++rr) {
      float p1 = 0.f, p2 = 0.f;
#pragma unroll
      for (int t = 0; t < 8; ++t) {
        p1 += acc[t][rr] * a1v[t];
        p2 += acc[t][rr] * a2v[t];
      }
#pragma unroll
      for (int o = 1; o < 16; o <<= 1) {
        p1 += __shfl_xor(p1, o);
        p2 += __shfl_xor(p2, o);
      }
      if (lm == 0) {
        zs[r0 + lk * 4 + rr] = p1;
        zd[r0 + lk * 4 + rr] = p2;
      }
    }
  }
}

// ---------------- CSR build -------------------------------------------------
__global__ void zero_int_kernel(int* __restrict__ p, int n) {
  int i = blockIdx.x * 256 + threadIdx.x;
  if (i < n) p[i] = 0;
}

__global__ void count_kernel(const int* __restrict__ dst, int* __restrict__ cnt,
                             int E) {
  int i = blockIdx.x * 256 + threadIdx.x;
  if (i < E) atomicAdd(&cnt[dst[i]], 1);
}

__global__ __launch_bounds__(256) void scan_partial(const int* __restrict__ cnt,
                                                    int* __restrict__ part,
                                                    int n) {
  __shared__ int sm[4];
  int base = blockIdx.x * 1024;
  int t = threadIdx.x;
  int s = 0;
#pragma unroll
  for (int i = 0; i < 4; ++i) {
    int idx = base + t + i * 256;
    s += (idx < n) ? cnt[idx] : 0;
  }
  for (int o = 32; o; o >>= 1) s += __shfl_xor(s, o);
  if ((t & 63) == 0) sm[t >> 6] = s;
  __syncthreads();
  if (t == 0) part[blockIdx.x] = sm[0] + sm[1] + sm[2] + sm[3];
}

__global__ void scan_top(int* __restrict__ part, int nb) {
  int t = threadIdx.x;
  int orig = (t < nb) ? part[t] : 0;
  int v = orig;
#pragma unroll
  for (int o = 1; o < 64; o <<= 1) {
    int u = __shfl_up(v, o);
    if (t >= o) v += u;
  }
  if (t < nb) part[t] = v - orig;
}

__global__ __launch_bounds__(256) void scan_final(
    const int* __restrict__ cnt, const int* __restrict__ part,
    int* __restrict__ offs, int* __restrict__ cursor, int n, int total) {
  __shared__ int sm[4];
  int base = blockIdx.x * 1024;
  int t = threadIdx.x;
  int idx = base + t * 4;
  int c0 = (idx + 0 < n) ? cnt[idx + 0] : 0;
  int c1 = (idx + 1 < n) ? cnt[idx + 1] : 0;
  int c2 = (idx + 2 < n) ? cnt[idx + 2] : 0;
  int c3 = (idx + 3 < n) ? cnt[idx + 3] : 0;
  int ts = c0 + c1 + c2 + c3;
  int v = ts;
#pragma unroll
  for (int o = 1; o < 64; o <<= 1) {
    int u = __shfl_up(v, o);
    if ((t & 63) >= o) v += u;
  }
  if ((t & 63) == 63) sm[t >> 6] = v;
  __syncthreads();
  int w = t >> 6;
  int waveoff = 0;
  if (w > 0) waveoff += sm[0];
  if (w > 1) waveoff += sm[1];
  if (w > 2) waveoff += sm[2];
  int run = v - ts + waveoff + part[blockIdx.x];
  if (idx + 0 < n) { offs[idx + 0] = run; cursor[idx + 0] = run; run += c0; }
  if (idx + 1 < n) { offs[idx + 1] = run; cursor[idx + 1] = run; run += c1; }
  if (idx + 2 < n) { offs[idx + 2] = run; cursor[idx + 2] = run; run += c2; }
  if (idx + 3 < n) { offs[idx + 3] = run; cursor[idx + 3] = run; run += c3; }
  if (blockIdx.x == 0 && t == 0) offs[n] = total;
}

// scatter + fused edge-logit: csr_e[p] = lrelu(zs[src]+zd[dst]+d*vc)
__global__ void scatter_kernel(const int* __restrict__ src,
                               const int* __restrict__ dst,
                               const float* __restrict__ dE,
                               const float* __restrict__ zs,
                               const float* __restrict__ zd,
                               const float* __restrict__ V,
                               const float* __restrict__ a,
                               int* __restrict__ cursor,
                               int* __restrict__ csr_src,
                               float* __restrict__ csr_e, int E) {
  int i = blockIdx.x * 256 + threadIdx.x;
  if (i < E) {
    int di = dst[i];
    int si = src[i];
    int p = atomicAdd(&cursor[di], 1);
    float vc = V[0] * a[2 * D];
    csr_src[p] = si;
    csr_e[p] = lrelu(zs[si] + zd[di] + dE[i] * vc);
  }
}

// ---------------- per-dst: softmax + weighted accumulate -------------------
// one 64-lane wave per dst; edge loop unrolled x8 with batched loads so the
// dependent chain (idx -> row gather) is paid once per 8 edges, not per edge.
__global__ __launch_bounds__(256) void gat_perdst(
    const unsigned short* __restrict__ z, const int* __restrict__ csr_src,
    const float* __restrict__ csr_e, const int* __restrict__ offs,
    float* __restrict__ out, int nd) {
  int n = blockIdx.x * 4 + (threadIdx.x >> 6);
  if (n >= nd) return;
  int lane = threadIdx.x & 63;
  int beg = offs[n], end = offs[n + 1];

  float m = -INFINITY;
  for (int j = beg + lane; j < end; j += 64) m = fmaxf(m, csr_e[j]);
  for (int o = 32; o; o >>= 1) m = fmaxf(m, __shfl_xor(m, o));

  float s = 0.f;
  float2 acc = make_float2(0.f, 0.f);
  const unsigned short* zp = z + lane * 2;
  int j = beg;
  for (; j + 8 <= end; j += 8) {
    int idx[8];
    float ev[8];
#pragma unroll
    for (int u = 0; u < 8; ++u) {
      idx[u] = csr_src[j + u];
      ev[u] = csr_e[j + u];
    }
    float2 zv[8];
#pragma unroll
    for (int u = 0; u < 8; ++u) zv[u] = loadZ2(zp + (size_t)idx[u] * D);
    float w[8];
#pragma unroll
    for (int u = 0; u < 8; ++u) w[u] = __expf(ev[u] - m);
#pragma unroll
    for (int u = 0; u < 8; ++u) {
      s += w[u];
      acc.x += w[u] * zv[u].x;
      acc.y += w[u] * zv[u].y;
    }
  }
  for (; j < end; ++j) {
    int srcj = csr_src[j];
    float w = __expf(csr_e[j] - m);
    float2 zv = loadZ2(zp + (size_t)srcj * D);
    s += w;
    acc.x += w * zv.x;
    acc.y += w * zv.y;
  }
  float inv = (s > 0.f) ? 1.f / s : 0.f;
  float2 ziv = *(const float2*)&out[(size_t)n * D + lane * 2];
  float2 o2;
  o2.x = fmaxf(ziv.x + acc.x * inv, 0.f);
  o2.y = fmaxf(ziv.y + acc.y * inv, 0.f);
  *(float2*)&out[(size_t)n * D + lane * 2] = o2;
}

// ---------------------------------------------------------------------------
static void run_layer(const float* h, int Nsrc, const float* dE,
                      const int* src, const int* dst, int nd, int E,
                      const __bf16* Wb, const __bf16* Ub, const float* V,
                      const float* a, unsigned short* z, float* zs, float* zd,
                      int* offs, int* cnt, int* cursor, int* part,
                      int* csr_src, float* csr_e, float* out,
                      hipStream_t stream) {
  gemm_mfma<unsigned short, true><<<(Nsrc + 63) / 64, 256, 0, stream>>>(
      h, Wb, z, a, zs, zd, Nsrc);
  gemm_mfma<float, false><<<(nd + 63) / 64, 256, 0, stream>>>(
      h, Ub, out, nullptr, nullptr, nullptr, nd);
  zero_int_kernel<<<(nd + 255) / 256, 256, 0, stream>>>(cnt, nd);
  count_kernel<<<(E + 255) / 256, 256, 0, stream>>>(dst, cnt, E);
  int nb = (nd + 1023) / 1024;  // <= 40
  scan_partial<<<nb, 256, 0, stream>>>(cnt, part, nd);
  scan_top<<<1, 64, 0, stream>>>(part, nb);
  scan_final<<<nb, 256, 0, stream>>>(cnt, part, offs, cursor, nd, E);
  scatter_kernel<<<(E + 255) / 256, 256, 0, stream>>>(
      src, dst, dE, zs, zd, V, a, cursor, csr_src, csr_e, E);
  gat_perdst<<<(nd + 3) / 4, 256, 0, stream>>>(z, csr_src, csr_e, offs, out,
                                               nd);
}

extern "C" void kernel_launch(void* const* d_in, const int* in_sizes, int n_in,
                              void* d_out, int out_size, void* d_ws,
                              size_t ws_size, hipStream_t stream) {
  const float* attr = (const float*)d_in[0];
  const float* d0 = (const float*)d_in[1];
  const float* d1 = (const float*)d_in[2];
  const int* src0 = (const int*)d_in[3];
  const int* dst0 = (const int*)d_in[4];
  const int* src1 = (const int*)d_in[5];
  const int* dst1 = (const int*)d_in[6];
  const float* W0 = (const float*)d_in[9];
  const float* U0 = (const float*)d_in[10];
  const float* V0 = (const float*)d_in[11];
  const float* a0 = (const float*)d_in[12];
  const float* W1 = (const float*)d_in[13];
  const float* U1 = (const float*)d_in[14];
  const float* V1 = (const float*)d_in[15];
  const float* a1 = (const float*)d_in[16];

  const int N0 = in_sizes[0] / D;  // 100000
  const int E0 = in_sizes[1];      // 640000
  const int E1 = in_sizes[2];      // 320000
  const int ND0 = 40000;
  const int ND1 = 20000;

  char* p = (char*)d_ws;
  auto alloc = [&](size_t bytes) {
    char* q = p;
    p += (bytes + 255) & ~(size_t)255;
    return q;
  };
  unsigned short* z = (unsigned short*)alloc((size_t)N0 * D * 2);
  float* h1 = (float*)alloc((size_t)ND0 * D * 4);
  float* zs = (float*)alloc((size_t)N0 * 4);
  float* zd = (float*)alloc((size_t)N0 * 4);
  int* offs = (int*)alloc((size_t)(ND0 + 1) * 4);
  int* cnt = (int*)alloc((size_t)ND0 * 4);
  int* cursor = (int*)alloc((size_t)ND0 * 4);
  int* part = (int*)alloc((size_t)64 * 4);
  int* csr_src = (int*)alloc((size_t)E0 * 4);
  float* csr_e = (float*)alloc((size_t)E0 * 4);
  __bf16* wb = (__bf16*)alloc((size_t)4 * D * D * 2);  // W0,U0,W1,U1 bf16
  (void)n_in;
  (void)out_size;
  (void)ws_size;

  float* out = (float*)d_out;

  cvt4_kernel<<<256, 256, 0, stream>>>(W0, U0, W1, U1, wb);
  const __bf16* W0b = wb;
  const __bf16* U0b = wb + 16384;
  const __bf16* W1b = wb + 32768;
  const __bf16* U1b = wb + 49152;

  run_layer(attr, N0, d0, src0, dst0, ND0, E0, W0b, U0b, V0, a0, z, zs, zd,
            offs, cnt, cursor, part, csr_src, csr_e, h1, stream);
  run_layer(h1, ND0, d1, src1, dst1, ND1, E1, W1b, U1b, V1, a1, z, zs, zd,
            offs, cnt, cursor, part, csr_src, csr_e, out, stream);
}

// Round 6
// 260.295 us; speedup vs baseline: 1.9897x; 1.0372x over previous
//
#include <hip/hip_runtime.h>
#include <math.h>

// ---------------------------------------------------------------------------
// 2-layer GAT on MI355X.
// R5 -> R6: (1) attr/h1 kept in bf16 so GEMM A-reads halve and the z+zi GEMMs
// fuse into one kernel (A-frags loaded once, no in-kernel f32->bf16 cvt);
// (2) scatter writes one packed 8B (src,e) instead of two 4B stores (write
// amplification 69MB -> ~40MB); (3) zi-L0 staged as bf16 in d_out, csr/h1
// alias the dead attr-bf16 region (footprint stays ~52.7MB, proven budget).
// ---------------------------------------------------------------------------

#define D 128

typedef __bf16 bf16x8 __attribute__((ext_vector_type(8)));
typedef float f32x4 __attribute__((ext_vector_type(4)));

static __device__ __forceinline__ float lrelu(float x) {
  return x >= 0.f ? x : 0.01f * x;
}
static __device__ __forceinline__ unsigned short f2bf(float v) {
  unsigned int u = __float_as_uint(v);
  u += 0x7fffu + ((u >> 16) & 1u);  // RNE
  return (unsigned short)(u >> 16);
}
static __device__ __forceinline__ float bf2f(unsigned short b) {
  return __uint_as_float((unsigned int)b << 16);
}

// float2 load/store over f32 or bf16-bits storage
static __device__ __forceinline__ float2 loadF2(const float* p) {
  return *(const float2*)p;
}
static __device__ __forceinline__ float2 loadF2(const unsigned short* p) {
  ushort2 t = *(const ushort2*)p;
  return make_float2(bf2f(t.x), bf2f(t.y));
}
static __device__ __forceinline__ void storeF2(float* p, float2 v) {
  *(float2*)p = v;
}
static __device__ __forceinline__ void storeF2(unsigned short* p, float2 v) {
  ushort2 t;
  t.x = f2bf(v.x);
  t.y = f2bf(v.y);
  *(ushort2*)p = t;
}
static __device__ __forceinline__ void storeZi(float* p, float v) { *p = v; }
static __device__ __forceinline__ void storeZi(unsigned short* p, float v) {
  *p = f2bf(v);
}

// ---- weight f32 -> bf16 (4 matrices of 128x128) ---------------------------
__global__ __launch_bounds__(256) void cvt4_kernel(
    const float* __restrict__ s0, const float* __restrict__ s1,
    const float* __restrict__ s2, const float* __restrict__ s3,
    __bf16* __restrict__ dst) {
  int idx = blockIdx.x * 256 + threadIdx.x;  // 0..65535
  const float* s = (idx < 16384) ? s0
                   : (idx < 32768) ? s1
                   : (idx < 49152) ? s2 : s3;
  dst[idx] = (__bf16)s[idx & 16383];
}

// ---- attr f32 -> bf16 (16B per thread) ------------------------------------
__global__ __launch_bounds__(256) void cvt_attr_kernel(
    const float* __restrict__ s, unsigned short* __restrict__ d, int n8) {
  int i = blockIdx.x * 256 + threadIdx.x;
  if (i >= n8) return;
  const float4* sp = (const float4*)s;
  float4 v0 = sp[i * 2], v1 = sp[i * 2 + 1];
  ushort4 a, b;
  a.x = f2bf(v0.x); a.y = f2bf(v0.y); a.z = f2bf(v0.z); a.w = f2bf(v0.w);
  b.x = f2bf(v1.x); b.y = f2bf(v1.y); b.z = f2bf(v1.z); b.w = f2bf(v1.w);
  ((ushort4*)d)[i * 2] = a;
  ((ushort4*)d)[i * 2 + 1] = b;
}

// ---------------- fused MFMA GEMM: z = A@Wb.T (+ zs/zd), zi = A@Ub.T -------
// A: [rows][128] bf16-bits. One wave = 16 rows x 128 cols; block = 4 waves.
// U-pass + zi-write only for rows < ndst. No LDS.
template <typename ZiT>
__global__ __launch_bounds__(256) void gemm_dual(
    const unsigned short* __restrict__ A, const __bf16* __restrict__ Wb,
    const __bf16* __restrict__ Ub, unsigned short* __restrict__ z,
    ZiT* __restrict__ zi, const float* __restrict__ a,
    float* __restrict__ zs, float* __restrict__ zd, int rows, int ndst) {
  const int wave = threadIdx.x >> 6;
  const int lane = threadIdx.x & 63;
  const int r0 = (blockIdx.x * 4 + wave) * 16;
  if (r0 >= rows) return;
  const int lm = lane & 15;
  const int lk = lane >> 4;

  // A fragments: lane holds A[r0+lm][kt*32 + lk*8 + 0..7]
  bf16x8 af[4];
  const unsigned short* ap = A + (size_t)(r0 + lm) * D + lk * 8;
#pragma unroll
  for (int kt = 0; kt < 4; ++kt) af[kt] = *(const bf16x8*)(ap + kt * 32);

  f32x4 acc[8];
#pragma unroll
  for (int t = 0; t < 8; ++t) acc[t] = (f32x4){0.f, 0.f, 0.f, 0.f};
#pragma unroll
  for (int kt = 0; kt < 4; ++kt) {
#pragma unroll
    for (int t = 0; t < 8; ++t) {
      bf16x8 bf =
          *(const bf16x8*)(Wb + (size_t)(t * 16 + lm) * D + kt * 32 + lk * 8);
      acc[t] = __builtin_amdgcn_mfma_f32_16x16x32_bf16(af[kt], bf, acc[t],
                                                       0, 0, 0);
    }
  }
  // write z (bf16): row = r0 + lk*4 + rr, col = t*16 + lm
#pragma unroll
  for (int t = 0; t < 8; ++t)
#pragma unroll
    for (int rr = 0; rr < 4; ++rr)
      z[(size_t)(r0 + lk * 4 + rr) * D + t * 16 + lm] = f2bf(acc[t][rr]);

  // zs/zd epilogue from acc
  {
    float a1v[8], a2v[8];
#pragma unroll
    for (int t = 0; t < 8; ++t) {
      a1v[t] = a[t * 16 + lm];
      a2v[t] = a[D + t * 16 + lm];
    }
#pragma unroll
    for (int rr = 0; rr < 4; ++rr) {
      float p1 = 0.f, p2 = 0.f;
#pragma unroll
      for (int t = 0; t < 8; ++t) {
        p1 += acc[t][rr] * a1v[t];
        p2 += acc[t][rr] * a2v[t];
      }
#pragma unroll
      for (int o = 1; o < 16; o <<= 1) {
        p1 += __shfl_xor(p1, o);
        p2 += __shfl_xor(p2, o);
      }
      if (lm == 0) {
        zs[r0 + lk * 4 + rr] = p1;
        zd[r0 + lk * 4 + rr] = p2;
      }
    }
  }

  // U pass (zi) only for dst rows
  if (r0 < ndst) {
#pragma unroll
    for (int t = 0; t < 8; ++t) acc[t] = (f32x4){0.f, 0.f, 0.f, 0.f};
#pragma unroll
    for (int kt = 0; kt < 4; ++kt) {
#pragma unroll
      for (int t = 0; t < 8; ++t) {
        bf16x8 bf = *(const bf16x8*)(Ub + (size_t)(t * 16 + lm) * D + kt * 32 +
                                     lk * 8);
        acc[t] = __builtin_amdgcn_mfma_f32_16x16x32_bf16(af[kt], bf, acc[t],
                                                         0, 0, 0);
      }
    }
#pragma unroll
    for (int t = 0; t < 8; ++t)
#pragma unroll
      for (int rr = 0; rr < 4; ++rr)
        storeZi(&zi[(size_t)(r0 + lk * 4 + rr) * D + t * 16 + lm],
                acc[t][rr]);
  }
}

// ---------------- CSR build -------------------------------------------------
__global__ void zero_int_kernel(int* __restrict__ p, int n) {
  int i = blockIdx.x * 256 + threadIdx.x;
  if (i < n) p[i] = 0;
}

__global__ void count_kernel(const int* __restrict__ dst, int* __restrict__ cnt,
                             int E) {
  int i = blockIdx.x * 256 + threadIdx.x;
  if (i < E) atomicAdd(&cnt[dst[i]], 1);
}

__global__ __launch_bounds__(256) void scan_partial(const int* __restrict__ cnt,
                                                    int* __restrict__ part,
                                                    int n) {
  __shared__ int sm[4];
  int base = blockIdx.x * 1024;
  int t = threadIdx.x;
  int s = 0;
#pragma unroll
  for (int i = 0; i < 4; ++i) {
    int idx = base + t + i * 256;
    s += (idx < n) ? cnt[idx] : 0;
  }
  for (int o = 32; o; o >>= 1) s += __shfl_xor(s, o);
  if ((t & 63) == 0) sm[t >> 6] = s;
  __syncthreads();
  if (t == 0) part[blockIdx.x] = sm[0] + sm[1] + sm[2] + sm[3];
}

__global__ void scan_top(int* __restrict__ part, int nb) {
  int t = threadIdx.x;
  int orig = (t < nb) ? part[t] : 0;
  int v = orig;
#pragma unroll
  for (int o = 1; o < 64; o <<= 1) {
    int u = __shfl_up(v, o);
    if (t >= o) v += u;
  }
  if (t < nb) part[t] = v - orig;
}

__global__ __launch_bounds__(256) void scan_final(
    const int* __restrict__ cnt, const int* __restrict__ part,
    int* __restrict__ offs, int* __restrict__ cursor, int n, int total) {
  __shared__ int sm[4];
  int base = blockIdx.x * 1024;
  int t = threadIdx.x;
  int idx = base + t * 4;
  int c0 = (idx + 0 < n) ? cnt[idx + 0] : 0;
  int c1 = (idx + 1 < n) ? cnt[idx + 1] : 0;
  int c2 = (idx + 2 < n) ? cnt[idx + 2] : 0;
  int c3 = (idx + 3 < n) ? cnt[idx + 3] : 0;
  int ts = c0 + c1 + c2 + c3;
  int v = ts;
#pragma unroll
  for (int o = 1; o < 64; o <<= 1) {
    int u = __shfl_up(v, o);
    if ((t & 63) >= o) v += u;
  }
  if ((t & 63) == 63) sm[t >> 6] = v;
  __syncthreads();
  int w = t >> 6;
  int waveoff = 0;
  if (w > 0) waveoff += sm[0];
  if (w > 1) waveoff += sm[1];
  if (w > 2) waveoff += sm[2];
  int run = v - ts + waveoff + part[blockIdx.x];
  if (idx + 0 < n) { offs[idx + 0] = run; cursor[idx + 0] = run; run += c0; }
  if (idx + 1 < n) { offs[idx + 1] = run; cursor[idx + 1] = run; run += c1; }
  if (idx + 2 < n) { offs[idx + 2] = run; cursor[idx + 2] = run; run += c2; }
  if (idx + 3 < n) { offs[idx + 3] = run; cursor[idx + 3] = run; run += c3; }
  if (blockIdx.x == 0 && t == 0) offs[n] = total;
}

// scatter + fused edge-logit, packed 8B write: csr[p] = (src, bits(e))
__global__ void scatter_kernel(const int* __restrict__ src,
                               const int* __restrict__ dst,
                               const float* __restrict__ dE,
                               const float* __restrict__ zs,
                               const float* __restrict__ zd,
                               const float* __restrict__ V,
                               const float* __restrict__ a,
                               int* __restrict__ cursor,
                               int2* __restrict__ csr, int E) {
  int i = blockIdx.x * 256 + threadIdx.x;
  if (i < E) {
    int di = dst[i];
    int si = src[i];
    int p = atomicAdd(&cursor[di], 1);
    float vc = V[0] * a[2 * D];
    float e = lrelu(zs[si] + zd[di] + dE[i] * vc);
    csr[p] = make_int2(si, __float_as_int(e));
  }
}

// ---------------- per-dst: softmax + weighted accumulate -------------------
// one 64-lane wave per dst; x8-batched loads. Reads zi from ziin, writes
// h = relu(zi + zn) to hout (may alias ziin).
template <typename OT>
__global__ __launch_bounds__(256) void gat_perdst(
    const unsigned short* __restrict__ z, const int2* __restrict__ csr,
    const int* __restrict__ offs, const OT* __restrict__ ziin,
    OT* __restrict__ hout, int nd) {
  int n = blockIdx.x * 4 + (threadIdx.x >> 6);
  if (n >= nd) return;
  int lane = threadIdx.x & 63;
  int beg = offs[n], end = offs[n + 1];

  float m = -INFINITY;
  for (int j = beg + lane; j < end; j += 64)
    m = fmaxf(m, __int_as_float(csr[j].y));
  for (int o = 32; o; o >>= 1) m = fmaxf(m, __shfl_xor(m, o));

  float s = 0.f;
  float2 acc = make_float2(0.f, 0.f);
  const unsigned short* zp = z + lane * 2;
  int j = beg;
  for (; j + 8 <= end; j += 8) {
    int2 pr[8];
#pragma unroll
    for (int u = 0; u < 8; ++u) pr[u] = csr[j + u];
    float2 zv[8];
#pragma unroll
    for (int u = 0; u < 8; ++u) zv[u] = loadF2(zp + (size_t)pr[u].x * D);
#pragma unroll
    for (int u = 0; u < 8; ++u) {
      float w = __expf(__int_as_float(pr[u].y) - m);
      s += w;
      acc.x += w * zv[u].x;
      acc.y += w * zv[u].y;
    }
  }
  for (; j < end; ++j) {
    int2 pr = csr[j];
    float w = __expf(__int_as_float(pr.y) - m);
    float2 zv = loadF2(zp + (size_t)pr.x * D);
    s += w;
    acc.x += w * zv.x;
    acc.y += w * zv.y;
  }
  float inv = (s > 0.f) ? 1.f / s : 0.f;
  float2 ziv = loadF2(ziin + (size_t)n * D + lane * 2);
  float2 o2;
  o2.x = fmaxf(ziv.x + acc.x * inv, 0.f);
  o2.y = fmaxf(ziv.y + acc.y * inv, 0.f);
  storeF2(hout + (size_t)n * D + lane * 2, o2);
}

// ---------------------------------------------------------------------------
static void build_csr(const int* dst, int nd, int E, int* cnt, int* offs,
                      int* cursor, int* part, hipStream_t stream) {
  zero_int_kernel<<<(nd + 255) / 256, 256, 0, stream>>>(cnt, nd);
  count_kernel<<<(E + 255) / 256, 256, 0, stream>>>(dst, cnt, E);
  int nb = (nd + 1023) / 1024;  // <= 40
  scan_partial<<<nb, 256, 0, stream>>>(cnt, part, nd);
  scan_top<<<1, 64, 0, stream>>>(part, nb);
  scan_final<<<nb, 256, 0, stream>>>(cnt, part, offs, cursor, nd, E);
}

extern "C" void kernel_launch(void* const* d_in, const int* in_sizes, int n_in,
                              void* d_out, int out_size, void* d_ws,
                              size_t ws_size, hipStream_t stream) {
  const float* attr = (const float*)d_in[0];
  const float* d0 = (const float*)d_in[1];
  const float* d1 = (const float*)d_in[2];
  const int* src0 = (const int*)d_in[3];
  const int* dst0 = (const int*)d_in[4];
  const int* src1 = (const int*)d_in[5];
  const int* dst1 = (const int*)d_in[6];
  const float* W0 = (const float*)d_in[9];
  const float* U0 = (const float*)d_in[10];
  const float* V0 = (const float*)d_in[11];
  const float* a0 = (const float*)d_in[12];
  const float* W1 = (const float*)d_in[13];
  const float* U1 = (const float*)d_in[14];
  const float* V1 = (const float*)d_in[15];
  const float* a1 = (const float*)d_in[16];

  const int N0 = in_sizes[0] / D;  // 100000
  const int E0 = in_sizes[1];      // 640000
  const int E1 = in_sizes[2];      // 320000
  const int ND0 = 40000;
  const int ND1 = 20000;

  char* p = (char*)d_ws;
  auto alloc = [&](size_t bytes) {
    char* q = p;
    p += (bytes + 255) & ~(size_t)255;
    return q;
  };
  unsigned short* hb0 = (unsigned short*)alloc((size_t)N0 * D * 2);  // 25.6MB
  unsigned short* z = (unsigned short*)alloc((size_t)N0 * D * 2);    // 25.6MB
  float* zs = (float*)alloc((size_t)N0 * 4);
  float* zd = (float*)alloc((size_t)N0 * 4);
  int* offs = (int*)alloc((size_t)(ND0 + 1) * 4);
  int* cnt = (int*)alloc((size_t)ND0 * 4);
  int* cursor = (int*)alloc((size_t)ND0 * 4);
  int* part = (int*)alloc((size_t)64 * 4);
  __bf16* wb = (__bf16*)alloc((size_t)4 * D * D * 2);  // W0,U0,W1,U1 bf16
  (void)n_in;
  (void)out_size;
  (void)ws_size;

  // aliases inside hb0 (dead after gemm_dual L0): csr at +0 (5.12MB),
  // h1 bf16 at +8MiB (10.24MB) -- disjoint.
  int2* csr = (int2*)hb0;
  unsigned short* h1b = hb0 + (size_t)4 * 1024 * 1024;

  float* out = (float*)d_out;

  cvt4_kernel<<<256, 256, 0, stream>>>(W0, U0, W1, U1, wb);
  const __bf16* W0b = wb;
  const __bf16* U0b = wb + 16384;
  const __bf16* W1b = wb + 32768;
  const __bf16* U1b = wb + 49152;
  cvt_attr_kernel<<<(N0 * D / 8 + 255) / 256, 256, 0, stream>>>(
      attr, hb0, N0 * D / 8);

  // ---- layer 0 (zi staged as bf16 bits in d_out; h1 -> h1b bf16) ----
  gemm_dual<unsigned short><<<(N0 + 63) / 64, 256, 0, stream>>>(
      hb0, W0b, U0b, z, (unsigned short*)d_out, a0, zs, zd, N0, ND0);
  build_csr(dst0, ND0, E0, cnt, offs, cursor, part, stream);
  scatter_kernel<<<(E0 + 255) / 256, 256, 0, stream>>>(
      src0, dst0, d0, zs, zd, V0, a0, cursor, csr, E0);
  gat_perdst<unsigned short><<<(ND0 + 3) / 4, 256, 0, stream>>>(
      z, csr, offs, (const unsigned short*)d_out, h1b, ND0);

  // ---- layer 1 (zi f32 in d_out, final in place) ----
  gemm_dual<float><<<(ND0 + 63) / 64, 256, 0, stream>>>(
      h1b, W1b, U1b, z, out, a1, zs, zd, ND0, ND1);
  build_csr(dst1, ND1, E1, cnt, offs, cursor, part, stream);
  scatter_kernel<<<(E1 + 255) / 256, 256, 0, stream>>>(
      src1, dst1, d1, zs, zd, V1, a1, cursor, csr, E1);
  gat_perdst<float><<<(ND1 + 3) / 4, 256, 0, stream>>>(z, csr, offs, out, out,
                                                       ND1);
}